// Round 19
// baseline (254.280 us; speedup 1.0000x reference)
//
#include <hip/hip_runtime.h>
#include <hip/hip_bf16.h>

#define N_TOK 16384
#define DIM   128
#define JT     64      // K/V tile (j) per iteration (v6-proven)

// LDS layouts:
// kb (16 segs/row, 256B rows): XOR swizzle ss = seg ^ (row&15) (R14: halved
//   SQ_LDS_BANK_CONFLICT vs &7; R15: 0 with vb padding).  Staged via
//   global_load_lds: LDS dest LINEAR (unit u -> row=u>>4, ss=u&15), source
//   address pre-swizzled (seg = ss ^ (row&15)) per m173.
// vb: PADDED rows, VROW=72 shorts (144B = 9x16B) -> PV reads conflict-free.
//   Padding is incompatible with global_load_lds (linear dest) -> reg-staged.
#define KROW 128       // kbuf: 64 rows [kv][d]
#define VROW 72        // vbuf: 128 rows [d][kv], padded

using bf16x8 = __attribute__((ext_vector_type(8)))  short;  // 8 bf16 (MFMA A/B frag)
using f32x4  = __attribute__((ext_vector_type(4)))  float;
using f32x16 = __attribute__((ext_vector_type(16))) float;  // 32x32 MFMA C/D frag
using i32x4  = __attribute__((ext_vector_type(4)))  int;
typedef int v2i __attribute__((ext_vector_type(2)));

static __device__ __forceinline__ unsigned short f2b(float f) {
    union { __hip_bfloat16 h; unsigned short u; } cv;
    cv.h = __float2bfloat16(f);   // RNE
    return cv.u;
}

// Packed 2x f32 -> 2x bf16 (RNE) in ONE VALU op (T12 recipe, m214v22-verified).
static __device__ __forceinline__ unsigned int cvtpk(float a, float b) {
    unsigned int r;
    asm("v_cvt_pk_bf16_f32 %0, %1, %2" : "=v"(r) : "v"(a), "v"(b));
    return r;
}

// Async global->LDS, 16B per lane (dest = wave-uniform base + lane*16;
// per-lane global source).  Counts in vmcnt; drained by the compiler's
// vmcnt(0) before s_barrier.
static __device__ __forceinline__ void gload_lds16(const void* g, void* l) {
    __builtin_amdgcn_global_load_lds(
        (const __attribute__((address_space(1))) void*)g,
        (__attribute__((address_space(3))) void*)l, 16, 0, 0);
}

// ---------------------------------------------------------------------------
__global__ __launch_bounds__(256)
void marker_kernel(float* out, float val)
{
    int i = blockIdx.x * 256 + threadIdx.x;
    if (i < N_TOK * DIM) out[i] = val;
}

// ---------------------------------------------------------------------------
// Prep: convert x and Wq/Wk/Wv fp32 -> bf16 ONCE (R18: saved ~5 us vs
// per-block conversion in qkv).  RNE via v_cvt_pk_bf16_f32.
// ---------------------------------------------------------------------------
__global__ __launch_bounds__(256)
void prep_kernel(const float* __restrict__ x,
                 const float* __restrict__ wq,
                 const float* __restrict__ wk,
                 const float* __restrict__ wv,
                 unsigned short* __restrict__ xb,
                 unsigned short* __restrict__ wb)
{
    size_t i = (size_t)blockIdx.x * 256 + threadIdx.x;   // float4-quad index
    if (i < (size_t)(N_TOK * DIM / 4)) {
        float4 v = reinterpret_cast<const float4*>(x)[i];
        uint2 r;
        r.x = cvtpk(v.x, v.y);
        r.y = cvtpk(v.z, v.w);
        reinterpret_cast<uint2*>(xb)[i] = r;
    }
    if (i < (size_t)(3 * DIM * DIM / 4)) {
        int z = (int)(i / (DIM * DIM / 4));
        size_t jq = i - (size_t)z * (DIM * DIM / 4);
        const float* w = (z == 0) ? wq : (z == 1) ? wk : wv;
        float4 v = reinterpret_cast<const float4*>(w)[jq];
        uint2 r;
        r.x = cvtpk(v.x, v.y);
        r.y = cvtpk(v.z, v.w);
        reinterpret_cast<uint2*>(wb)[i] = r;
    }
}

// ---------------------------------------------------------------------------
// QKV: Q = xb@Wb^T per z, Vt = (xb@Wvb^T)^T.  bf16 in, bf16 out.
// ---------------------------------------------------------------------------
__global__ __launch_bounds__(256)
void qkv_kernel(const unsigned short* __restrict__ xb,
                const unsigned short* __restrict__ wb,
                unsigned short* __restrict__ Q,
                unsigned short* __restrict__ K,
                unsigned short* __restrict__ Vt)
{
    const int t = threadIdx.x;
    const int wave = t >> 6, lane = t & 63;
    const int ln = lane & 15, quad = lane >> 4, q8 = quad * 8;
    const int z = blockIdx.y;
    const unsigned short* W = wb + (size_t)z * DIM * DIM;
    const int r0 = blockIdx.x * 64 + wave * 16;

    bf16x8 a[4];
#pragma unroll
    for (int ks = 0; ks < 4; ++ks)
        a[ks] = *reinterpret_cast<const bf16x8*>(
            &xb[(size_t)(r0 + ln) * DIM + ks * 32 + q8]);

    f32x4 acc[8];
#pragma unroll
    for (int nt = 0; nt < 8; ++nt) acc[nt] = f32x4{0.f, 0.f, 0.f, 0.f};

#pragma unroll
    for (int nt = 0; nt < 8; ++nt)
#pragma unroll
        for (int ks = 0; ks < 4; ++ks) {
            bf16x8 b = *reinterpret_cast<const bf16x8*>(
                &W[(size_t)(nt * 16 + ln) * DIM + ks * 32 + q8]);
            acc[nt] = __builtin_amdgcn_mfma_f32_16x16x32_bf16(a[ks], b, acc[nt], 0, 0, 0);
        }

#pragma unroll
    for (int nt = 0; nt < 8; ++nt) {
        const int col = nt * 16 + ln;
        if (z == 2) {
            ushort4 v4;
            v4.x = f2b(acc[nt][0]); v4.y = f2b(acc[nt][1]);
            v4.z = f2b(acc[nt][2]); v4.w = f2b(acc[nt][3]);
            *reinterpret_cast<ushort4*>(&Vt[(size_t)col * N_TOK + r0 + quad * 4]) = v4;
        } else {
            unsigned short* dst = (z == 0) ? Q : K;
#pragma unroll
            for (int r = 0; r < 4; ++r)
                dst[(size_t)(r0 + quad * 4 + r) * DIM + col] = f2b(acc[nt][r]);
        }
    }
}

// ---------------------------------------------------------------------------
// Flash attention v15: v13 (177.8 us measured) with K staging moved to
// global_load_lds (async DMA, pre-swizzled source).  Rationale: LDS-op
// arithmetic shows the pipe at ~115% of tile time (320 b128 ops x 12 cyc
// vs 3334 cyc/tile/CU); the 8 staging ds_writes/wave are the removable 20%
// (K half of them).  Also: -16 VGPR, -4 issue slots, latency hidden under
// the full tile.  V stays reg-staged (padded rows).
// Hazards: async writes hit kb[c^1] whose readers finished at the previous
// barrier; the compiler's vmcnt(0)-before-s_barrier drains completions
// before the next tile reads.
// ---------------------------------------------------------------------------
__global__ __launch_bounds__(256, 2)
void flash_kernel(const unsigned short* __restrict__ Q,
                  const unsigned short* __restrict__ K,
                  const unsigned short* __restrict__ Vt,
                  const unsigned int* __restrict__ u32,
                  int jspan,
                  float* __restrict__ pO, float* __restrict__ pl,
                  float* __restrict__ out)
{
    __shared__ __align__(16) unsigned short kb[2][JT * KROW];   // 32 KB
    __shared__ __align__(16) unsigned short vb[2][DIM * VROW];  // 36 KB
    __shared__ __align__(16) int   ub[2][JT];                   // 512 B
    __shared__ __align__(16) float lbuf[4][32];                 // 512 B -> 69 KB

    const int t = threadIdx.x;
    const int wave = t >> 6, lane = t & 63;
    const int q31 = lane & 31, hi = lane >> 5;
    const int r0w = blockIdx.x * 128 + wave * 32;    // this wave's q-base
    const int split = blockIdx.y;
    const int j0 = split * jspan;
    const int j1 = j0 + jspan;

    const float lscale = 1.4426950408889634f * 0.08838834764831845f; // log2(e)/sqrt(128)
    const float cbias  = 5.0f * 1.4426950408889634f - 16.0f;         // same-user
    const float cnob   = -16.0f;                                     // different user

    // uid dtype sniff (uniform verdict on every thread)
    bool i64 = true;
    for (int k = 0; k < 64; ++k) i64 = i64 && (u32[2 * k + 1] == 0u);

    // Q fragments: B[n=q31][k = dt*16 + hi*8 + j]
    bf16x8 qf[8];
#pragma unroll
    for (int dt = 0; dt < 8; ++dt)
        qf[dt] = *reinterpret_cast<const bf16x8*>(
            &Q[(size_t)(r0w + q31) * DIM + dt * 16 + hi * 8]);

    const int uq = (int)(i64 ? u32[2 * (r0w + q31)] : u32[r0w + q31]);

    f32x16 o[4];
#pragma unroll
    for (int nt = 0; nt < 4; ++nt)
#pragma unroll
        for (int r = 0; r < 16; ++r) o[nt][r] = 0.f;
    float lsum = 0.f;

    // ---- prologue: stage tile j0 into buffer 0 ----
    {
#pragma unroll
        for (int p = 0; p < 4; ++p) {
            int slot = p * 256 + t;
            int row = slot >> 4, ss = slot & 15;
            int seg = ss ^ (row & 15);               // pre-swizzled source
            gload_lds16(&K[(size_t)(j0 + row) * DIM + seg * 8], &kb[0][slot * 8]);
        }
#pragma unroll
        for (int p = 0; p < 4; ++p) {
            int slot = p * 256 + t;
            int row = slot >> 3, seg = slot & 7;
            *reinterpret_cast<uint4*>(&vb[0][row * VROW + seg * 8]) =
                *reinterpret_cast<const uint4*>(&Vt[(size_t)row * N_TOK + j0 + seg * 8]);
        }
        if (t < JT) {
            int i = j0 + t;
            ub[0][t] = (int)(i64 ? u32[2 * i] : u32[i]);
        }
    }
    __syncthreads();   // vmcnt(0) drain covers the async K loads

    int c = 0;
    for (int j = j0; j < j1; j += JT) {
        int jn = j + JT;
        if (jn >= j1) jn = j0;   // dummy wrap on last iter

        // ---- issue async K loads for next tile into kb[c^1] (linear dest,
        //      pre-swizzled src); land before this tile's closing barrier ----
#pragma unroll
        for (int p = 0; p < 4; ++p) {
            int slot = p * 256 + t;
            int row = slot >> 4, ss = slot & 15;
            int seg = ss ^ (row & 15);
            gload_lds16(&K[(size_t)(jn + row) * DIM + seg * 8], &kb[c ^ 1][slot * 8]);
        }
        // ---- prefetch next V tile + uids into regs ----
        uint4 vreg[4];
#pragma unroll
        for (int p = 0; p < 4; ++p) {
            int slot = p * 256 + t;
            int row = slot >> 3, seg = slot & 7;
            vreg[p] = *reinterpret_cast<const uint4*>(&Vt[(size_t)row * N_TOK + jn + seg * 8]);
        }
        int ureg = 0;
        if (t < JT) ureg = (int)(i64 ? u32[2 * (jn + t)] : u32[jn + t]);

        // ---- swapped QK^T: S^T[kv][q] accumulated over 8 dt ----
        // sc: (32+q31)&15 == q31&15, so k0/k1 share sc.
        f32x16 s0v, s1v;
#pragma unroll
        for (int r = 0; r < 16; ++r) { s0v[r] = 0.f; s1v[r] = 0.f; }
        __builtin_amdgcn_s_setprio(1);
#pragma unroll
        for (int dt = 0; dt < 8; ++dt) {
            int sc = (dt * 2 + hi) ^ (q31 & 15);
            bf16x8 k0 = *reinterpret_cast<const bf16x8*>(&kb[c][q31 * KROW + sc * 8]);
            bf16x8 k1 = *reinterpret_cast<const bf16x8*>(&kb[c][(32 + q31) * KROW + sc * 8]);
            s0v = __builtin_amdgcn_mfma_f32_32x32x16_bf16(k0, qf[dt], s0v, 0, 0, 0);
            s1v = __builtin_amdgcn_mfma_f32_32x32x16_bf16(k1, qf[dt], s1v, 0, 0, 0);
        }
        __builtin_amdgcn_s_setprio(0);

        // ---- softmax + packed cvt + permlane32_swap exchange -> pa[4] ----
        bf16x8 pa[4];
#pragma unroll
        for (int kv32 = 0; kv32 < 2; ++kv32) {
            i32x4 ukg[4];
#pragma unroll
            for (int g = 0; g < 4; ++g)
                ukg[g] = *reinterpret_cast<const i32x4*>(&ub[c][32 * kv32 + 8 * g + 4 * hi]);

            unsigned int dw[4][2];
#pragma unroll
            for (int g = 0; g < 4; ++g) {
                float v0 = __builtin_fmaf((kv32 ? s1v : s0v)[4 * g + 0], lscale,
                                          (uq == ukg[g][0]) ? cbias : cnob);
                float v1 = __builtin_fmaf((kv32 ? s1v : s0v)[4 * g + 1], lscale,
                                          (uq == ukg[g][1]) ? cbias : cnob);
                float v2 = __builtin_fmaf((kv32 ? s1v : s0v)[4 * g + 2], lscale,
                                          (uq == ukg[g][2]) ? cbias : cnob);
                float v3 = __builtin_fmaf((kv32 ? s1v : s0v)[4 * g + 3], lscale,
                                          (uq == ukg[g][3]) ? cbias : cnob);
                float p0 = __builtin_amdgcn_exp2f(v0);
                float p1 = __builtin_amdgcn_exp2f(v1);
                float p2 = __builtin_amdgcn_exp2f(v2);
                float p3 = __builtin_amdgcn_exp2f(v3);
                lsum += (p0 + p1) + (p2 + p3);
                dw[g][0] = cvtpk(p0, p1);    // low16=p0, high16=p1 (RNE)
                dw[g][1] = cvtpk(p2, p3);
            }

            // swap(dw[2kt], dw[2kt+1]): X'=h'=0 halves, Y'=h'=1 halves.
#pragma unroll
            for (int kt = 0; kt < 2; ++kt) {
                v2i sw0 = __builtin_amdgcn_permlane32_swap(
                    (int)dw[2 * kt][0], (int)dw[2 * kt + 1][0], false, false);
                v2i sw1 = __builtin_amdgcn_permlane32_swap(
                    (int)dw[2 * kt][1], (int)dw[2 * kt + 1][1], false, false);
                union { unsigned int u[4]; bf16x8 v; } pu;
                pu.u[0] = (unsigned int)sw0[0];
                pu.u[1] = (unsigned int)sw1[0];
                pu.u[2] = (unsigned int)sw0[1];
                pu.u[3] = (unsigned int)sw1[1];
                pa[kv32 * 2 + kt] = pu.v;
            }
        }

        // ---- write prefetched uids (K is already in flight via DMA) ----
        if (t < JT) ub[c ^ 1][t] = ureg;

        // ---- PV: O[q][d] += P @ V  (B[n=d][k=kv] from vb rows) ----
        __builtin_amdgcn_s_setprio(1);
#pragma unroll
        for (int nt = 0; nt < 4; ++nt) {
            int row = nt * 32 + q31;                 // d-row of vb
#pragma unroll
            for (int ktg = 0; ktg < 4; ++ktg) {
                int seg = ktg * 2 + hi;              // padded rows: no XOR
                bf16x8 b = *reinterpret_cast<const bf16x8*>(&vb[c][row * VROW + seg * 8]);
                o[nt] = __builtin_amdgcn_mfma_f32_32x32x16_bf16(pa[ktg], b, o[nt], 0, 0, 0);
            }
        }
        __builtin_amdgcn_s_setprio(0);

        // ---- write prefetched V into idle buffer ----
#pragma unroll
        for (int p = 0; p < 4; ++p) {
            int slot = p * 256 + t;
            int row = slot >> 3, seg = slot & 7;
            *reinterpret_cast<uint4*>(&vb[c ^ 1][row * VROW + seg * 8]) = vreg[p];
        }

        __syncthreads();   // single barrier: drains async K + fences buffers
        c ^= 1;
    }

    // ---- epilogue ----
    lsum += __shfl_xor(lsum, 32, 64);   // combine the two k-halves of q=q31

    if (out != nullptr) {
        bool lbad = !(lsum > 0.f) || !(lsum < 3.0e38f);
        float inv = 1.0f / lsum;
        if (hi == 0) lbuf[wave][q31] = lbad ? -1.0f : inv;
        __syncthreads();
        f32x4 ivg[4];
#pragma unroll
        for (int g = 0; g < 4; ++g)
            ivg[g] = *reinterpret_cast<const f32x4*>(&lbuf[wave][8 * g + 4 * hi]);
#pragma unroll
        for (int nt = 0; nt < 4; ++nt)
#pragma unroll
            for (int g = 0; g < 4; ++g)
#pragma unroll
                for (int i = 0; i < 4; ++i) {
                    int row = r0w + 8 * g + 4 * hi + i;
                    float iv = ivg[g][i];
                    float v = o[nt][4 * g + i] * iv;
                    if (v != v) v = 12345.0f;
                    if (iv < 0.f) v = 23456.0f;
                    out[(size_t)row * DIM + nt * 32 + q31] = v;
                }
    } else {
        const size_t base = (size_t)split * N_TOK;
        if (hi == 0) pl[base + r0w + q31] = lsum;
#pragma unroll
        for (int nt = 0; nt < 4; ++nt)
#pragma unroll
            for (int g = 0; g < 4; ++g)
#pragma unroll
                for (int i = 0; i < 4; ++i) {
                    int row = r0w + 8 * g + 4 * hi + i;
                    pO[(base + row) * DIM + nt * 32 + q31] = o[nt][4 * g + i];
                }
    }
}

// ---------------------------------------------------------------------------
// Merge: out[row] = (sum_s pO[s][row]) / (sum_s pl[s][row]).
// ---------------------------------------------------------------------------
__global__ __launch_bounds__(256)
void merge_kernel(const float* __restrict__ pO, const float* __restrict__ pl,
                  float* __restrict__ out, int ns)
{
    const int t = threadIdx.x;
    const int wave = t >> 6, lane = t & 63;
    const int row = blockIdx.x * 4 + wave;
    const int c = lane * 2;

    float l = 0.f;
    for (int s = 0; s < ns; ++s) l += pl[(size_t)s * N_TOK + row];
    bool lbad = !(l > 0.f) || !(l < 3.0e38f);
    float inv = 1.0f / l;

    float a0 = 0.f, a1 = 0.f;
    for (int s = 0; s < ns; ++s) {
        const float2 v = *reinterpret_cast<const float2*>(
            &pO[((size_t)s * N_TOK + row) * DIM + c]);
        a0 += v.x; a1 += v.y;
    }
    float v0 = a0 * inv, v1 = a1 * inv;
    if (v0 != v0) v0 = 12345.0f;
    if (v1 != v1) v1 = 12345.0f;
    if (lbad) { v0 = 23456.0f; v1 = 23456.0f; }
    float2 res; res.x = v0; res.y = v1;
    *reinterpret_cast<float2*>(&out[(size_t)row * DIM + c]) = res;
}

// ---------------------------------------------------------------------------
extern "C" void kernel_launch(void* const* d_in, const int* in_sizes, int n_in,
                              void* d_out, int out_size, void* d_ws, size_t ws_size,
                              hipStream_t stream)
{
    float* out = (float*)d_out;

    bool ok = (n_in == 5) &&
              in_sizes[0] == N_TOK * DIM && in_sizes[1] == N_TOK &&
              in_sizes[2] == DIM * DIM && in_sizes[3] == DIM * DIM &&
              in_sizes[4] == DIM * DIM && out_size == N_TOK * DIM;
    if (!ok) { marker_kernel<<<8192, 256, 0, stream>>>(out, 5555.f); return; }

    const float*        xf  = (const float*)d_in[0];
    const unsigned int* u32 = (const unsigned int*)d_in[1];
    const float*        wqf = (const float*)d_in[2];
    const float*        wkf = (const float*)d_in[3];
    const float*        wvf = (const float*)d_in[4];

    char* ws = (char*)d_ws;
    size_t off = 0;
    unsigned short* Q  = (unsigned short*)(ws + off); off += (size_t)N_TOK * DIM * 2;   // 4 MB
    unsigned short* K  = (unsigned short*)(ws + off); off += (size_t)N_TOK * DIM * 2;   // 4 MB
    unsigned short* Vt = (unsigned short*)(ws + off); off += (size_t)N_TOK * DIM * 2;   // 4 MB
    unsigned short* xb = (unsigned short*)(ws + off); off += (size_t)N_TOK * DIM * 2;   // 4 MB
    unsigned short* wb = (unsigned short*)(ws + off); off += (size_t)3 * DIM * DIM * 2; // 96 KB

    if (ws_size < off) { marker_kernel<<<8192, 256, 0, stream>>>(out, 4444.f); return; }

    // R8-proven config: nsplit=4, grid (128,4) = 512 blocks = 2 blocks/CU.
    const size_t per_split = (size_t)N_TOK * DIM * 4 + (size_t)N_TOK * 4;
    int nsplit = 1;
    if (ws_size >= off + 4 * per_split)      nsplit = 4;
    else if (ws_size >= off + 2 * per_split) nsplit = 2;

    prep_kernel<<<N_TOK * DIM / 4 / 256, 256, 0, stream>>>(xf, wqf, wkf, wvf, xb, wb);
    qkv_kernel<<<dim3(N_TOK / 64, 3), 256, 0, stream>>>(xb, wb, Q, K, Vt);

    if (nsplit >= 2) {
        float* pO = (float*)(ws + off);
        float* pl = (float*)(ws + off + (size_t)nsplit * N_TOK * DIM * 4);
        flash_kernel<<<dim3(N_TOK / 128, nsplit), 256, 0, stream>>>(
            Q, K, Vt, u32, N_TOK / nsplit, pO, pl, nullptr);
        merge_kernel<<<N_TOK / 4, 256, 0, stream>>>(pO, pl, out, nsplit);
    } else {
        flash_kernel<<<dim3(N_TOK / 128, 1), 256, 0, stream>>>(
            Q, K, Vt, u32, N_TOK, nullptr, nullptr, out);
    }
}

// Round 20
// 250.356 us; speedup vs baseline: 1.0157x; 1.0157x over previous
//
#include <hip/hip_runtime.h>
#include <hip/hip_bf16.h>

#define N_TOK 16384
#define DIM   128
#define JT     64      // K/V tile (j) per iteration (v6-proven)

// LDS layouts:
// kb (16 segs/row, 256B rows): XOR swizzle ss = seg ^ (row&15) (R14: halved
//   SQ_LDS_BANK_CONFLICT vs &7).
// vb: PADDED rows, VROW=72 shorts (144B = 9x16B) -> group(row,seg) cycles all
//   8 bank-groups (R15: SQ_LDS_BANK_CONFLICT == 0).
// NOTE (R19): K staging via global_load_lds REGRESSED (+8 us flash) -- DMA
// writes consume the same LDS banks and drain serially at the barrier.
// Reg-staged kreg path restored (R18's proven 177.6 us flash).
#define KROW 128       // kbuf: 64 rows [kv][d]
#define VROW 72        // vbuf: 128 rows [d][kv], padded

using bf16x8 = __attribute__((ext_vector_type(8)))  short;  // 8 bf16 (MFMA A/B frag)
using f32x4  = __attribute__((ext_vector_type(4)))  float;
using f32x16 = __attribute__((ext_vector_type(16))) float;  // 32x32 MFMA C/D frag
using i32x4  = __attribute__((ext_vector_type(4)))  int;
typedef int v2i __attribute__((ext_vector_type(2)));

static __device__ __forceinline__ unsigned short f2b(float f) {
    union { __hip_bfloat16 h; unsigned short u; } cv;
    cv.h = __float2bfloat16(f);   // RNE
    return cv.u;
}

// Packed 2x f32 -> 2x bf16 (RNE) in ONE VALU op (T12 recipe, m214v22-verified).
// dst low16 = cvt(a), high16 = cvt(b).
static __device__ __forceinline__ unsigned int cvtpk(float a, float b) {
    unsigned int r;
    asm("v_cvt_pk_bf16_f32 %0, %1, %2" : "=v"(r) : "v"(a), "v"(b));
    return r;
}

// ---------------------------------------------------------------------------
__global__ __launch_bounds__(256)
void marker_kernel(float* out, float val)
{
    int i = blockIdx.x * 256 + threadIdx.x;
    if (i < N_TOK * DIM) out[i] = val;
}

// ---------------------------------------------------------------------------
// Prep: convert x (fp32 -> bf16) and Wq/Wk/Wv (fp32 -> bf16) ONCE.
// (R18: saved ~5 us vs per-block conversion in qkv.)  RNE via
// v_cvt_pk_bf16_f32 -> bit-identical to the old in-kernel f2b path.
// ---------------------------------------------------------------------------
__global__ __launch_bounds__(256)
void prep_kernel(const float* __restrict__ x,
                 const float* __restrict__ wq,
                 const float* __restrict__ wk,
                 const float* __restrict__ wv,
                 unsigned short* __restrict__ xb,
                 unsigned short* __restrict__ wb)
{
    size_t i = (size_t)blockIdx.x * 256 + threadIdx.x;   // float4-quad index
    if (i < (size_t)(N_TOK * DIM / 4)) {
        float4 v = reinterpret_cast<const float4*>(x)[i];
        uint2 r;
        r.x = cvtpk(v.x, v.y);
        r.y = cvtpk(v.z, v.w);
        reinterpret_cast<uint2*>(xb)[i] = r;
    }
    if (i < (size_t)(3 * DIM * DIM / 4)) {
        int z = (int)(i / (DIM * DIM / 4));
        size_t jq = i - (size_t)z * (DIM * DIM / 4);
        const float* w = (z == 0) ? wq : (z == 1) ? wk : wv;
        float4 v = reinterpret_cast<const float4*>(w)[jq];
        uint2 r;
        r.x = cvtpk(v.x, v.y);
        r.y = cvtpk(v.z, v.w);
        reinterpret_cast<uint2*>(wb)[i] = r;
    }
}

// ---------------------------------------------------------------------------
// QKV: Q = xb@Wb^T per z, Vt = (xb@Wvb^T)^T.  bf16 in (pre-converted), bf16 out.
// Pure MFMA + 16B fragment loads; zero conversion VALU in the hot path.
// R14 direct-store epilogue (R15 A/B: LDS bounce cost +4 us -- reverted).
// ---------------------------------------------------------------------------
__global__ __launch_bounds__(256)
void qkv_kernel(const unsigned short* __restrict__ xb,
                const unsigned short* __restrict__ wb,
                unsigned short* __restrict__ Q,
                unsigned short* __restrict__ K,
                unsigned short* __restrict__ Vt)
{
    const int t = threadIdx.x;
    const int wave = t >> 6, lane = t & 63;
    const int ln = lane & 15, quad = lane >> 4, q8 = quad * 8;
    const int z = blockIdx.y;
    const unsigned short* W = wb + (size_t)z * DIM * DIM;
    const int r0 = blockIdx.x * 64 + wave * 16;

    bf16x8 a[4];
#pragma unroll
    for (int ks = 0; ks < 4; ++ks)
        a[ks] = *reinterpret_cast<const bf16x8*>(
            &xb[(size_t)(r0 + ln) * DIM + ks * 32 + q8]);

    f32x4 acc[8];
#pragma unroll
    for (int nt = 0; nt < 8; ++nt) acc[nt] = f32x4{0.f, 0.f, 0.f, 0.f};

#pragma unroll
    for (int nt = 0; nt < 8; ++nt)
#pragma unroll
        for (int ks = 0; ks < 4; ++ks) {
            bf16x8 b = *reinterpret_cast<const bf16x8*>(
                &W[(size_t)(nt * 16 + ln) * DIM + ks * 32 + q8]);
            acc[nt] = __builtin_amdgcn_mfma_f32_16x16x32_bf16(a[ks], b, acc[nt], 0, 0, 0);
        }

#pragma unroll
    for (int nt = 0; nt < 8; ++nt) {
        const int col = nt * 16 + ln;
        if (z == 2) {
            ushort4 v4;
            v4.x = f2b(acc[nt][0]); v4.y = f2b(acc[nt][1]);
            v4.z = f2b(acc[nt][2]); v4.w = f2b(acc[nt][3]);
            *reinterpret_cast<ushort4*>(&Vt[(size_t)col * N_TOK + r0 + quad * 4]) = v4;
        } else {
            unsigned short* dst = (z == 0) ? Q : K;
#pragma unroll
            for (int r = 0; r < 4; ++r)
                dst[(size_t)(r0 + quad * 4 + r) * DIM + col] = f2b(acc[nt][r]);
        }
    }
}

// ---------------------------------------------------------------------------
// Flash attention v13 (R17/R18-proven: 177.6-178.8 us):
// zero-conflict LDS (kb seg^(row&15); vb VROW=72 padded), swapped QK^T
// (S^T = mfma_32x32x16(A=K, B=Q); lane owns P[q=lane&31][kv=crow],
// crow=(reg&3)+8*(reg>>2)+4*hi, m74/m101), fixed-offset in-register softmax
// (p=exp2(s*lscale-16+bias)), v_cvt_pk_bf16_f32 pack, permlane32_swap
// exchange, PV from vb[d][kv] rows, reg-staged dbuf K/V/u, 1 barrier/tile.
// Geometry: 4 waves x 256 thr, 128 q-rows/block, grid (128, nsplit=4).
//
// Structural note (R19 analysis): the LDS pipe is the binding resource
// (~32 b128 reads + 8 staging writes /wave/tile = 77-115% of tile time);
// more q-reuse per wave would need ~290 VGPR -> spill.  This is the
// converged form of this structure.
// ---------------------------------------------------------------------------
__global__ __launch_bounds__(256, 2)
void flash_kernel(const unsigned short* __restrict__ Q,
                  const unsigned short* __restrict__ K,
                  const unsigned short* __restrict__ Vt,
                  const unsigned int* __restrict__ u32,
                  int jspan,
                  float* __restrict__ pO, float* __restrict__ pl,
                  float* __restrict__ out)
{
    __shared__ __align__(16) unsigned short kb[2][JT * KROW];   // 32 KB
    __shared__ __align__(16) unsigned short vb[2][DIM * VROW];  // 36 KB
    __shared__ __align__(16) int   ub[2][JT];                   // 512 B
    __shared__ __align__(16) float lbuf[4][32];                 // 512 B -> 69 KB

    const int t = threadIdx.x;
    const int wave = t >> 6, lane = t & 63;
    const int q31 = lane & 31, hi = lane >> 5;
    const int r0w = blockIdx.x * 128 + wave * 32;    // this wave's q-base
    const int split = blockIdx.y;
    const int j0 = split * jspan;
    const int j1 = j0 + jspan;

    const float lscale = 1.4426950408889634f * 0.08838834764831845f; // log2(e)/sqrt(128)
    const float cbias  = 5.0f * 1.4426950408889634f - 16.0f;         // same-user
    const float cnob   = -16.0f;                                     // different user

    // uid dtype sniff (uniform verdict on every thread)
    bool i64 = true;
    for (int k = 0; k < 64; ++k) i64 = i64 && (u32[2 * k + 1] == 0u);

    // Q fragments: B[n=q31][k = dt*16 + hi*8 + j]
    bf16x8 qf[8];
#pragma unroll
    for (int dt = 0; dt < 8; ++dt)
        qf[dt] = *reinterpret_cast<const bf16x8*>(
            &Q[(size_t)(r0w + q31) * DIM + dt * 16 + hi * 8]);

    const int uq = (int)(i64 ? u32[2 * (r0w + q31)] : u32[r0w + q31]);

    f32x16 o[4];
#pragma unroll
    for (int nt = 0; nt < 4; ++nt)
#pragma unroll
        for (int r = 0; r < 16; ++r) o[nt][r] = 0.f;
    float lsum = 0.f;

    // ---- prologue: stage tile j0 into buffer 0 ----
    {
#pragma unroll
        for (int p = 0; p < 4; ++p) {
            int slot = p * 256 + t;
            int row = slot >> 4, seg = slot & 15;
            int ss = seg ^ (row & 15);
            *reinterpret_cast<uint4*>(&kb[0][row * KROW + ss * 8]) =
                *reinterpret_cast<const uint4*>(&K[(size_t)(j0 + row) * DIM + seg * 8]);
        }
#pragma unroll
        for (int p = 0; p < 4; ++p) {
            int slot = p * 256 + t;
            int row = slot >> 3, seg = slot & 7;
            *reinterpret_cast<uint4*>(&vb[0][row * VROW + seg * 8]) =
                *reinterpret_cast<const uint4*>(&Vt[(size_t)row * N_TOK + j0 + seg * 8]);
        }
        if (t < JT) {
            int i = j0 + t;
            ub[0][t] = (int)(i64 ? u32[2 * i] : u32[i]);
        }
    }
    __syncthreads();

    int c = 0;
    for (int j = j0; j < j1; j += JT) {
        int jn = j + JT;
        if (jn >= j1) jn = j0;   // dummy wrap on last iter

        // ---- prefetch next tile into regs ----
        uint4 kreg[4];
#pragma unroll
        for (int p = 0; p < 4; ++p) {
            int slot = p * 256 + t;
            int row = slot >> 4, seg = slot & 15;
            kreg[p] = *reinterpret_cast<const uint4*>(&K[(size_t)(jn + row) * DIM + seg * 8]);
        }
        uint4 vreg[4];
#pragma unroll
        for (int p = 0; p < 4; ++p) {
            int slot = p * 256 + t;
            int row = slot >> 3, seg = slot & 7;
            vreg[p] = *reinterpret_cast<const uint4*>(&Vt[(size_t)row * N_TOK + jn + seg * 8]);
        }
        int ureg = 0;
        if (t < JT) ureg = (int)(i64 ? u32[2 * (jn + t)] : u32[jn + t]);

        // ---- swapped QK^T: S^T[kv][q] accumulated over 8 dt ----
        // sc: (32+q31)&15 == q31&15, so k0/k1 share sc.
        f32x16 s0v, s1v;
#pragma unroll
        for (int r = 0; r < 16; ++r) { s0v[r] = 0.f; s1v[r] = 0.f; }
        __builtin_amdgcn_s_setprio(1);
#pragma unroll
        for (int dt = 0; dt < 8; ++dt) {
            int sc = (dt * 2 + hi) ^ (q31 & 15);
            bf16x8 k0 = *reinterpret_cast<const bf16x8*>(&kb[c][q31 * KROW + sc * 8]);
            bf16x8 k1 = *reinterpret_cast<const bf16x8*>(&kb[c][(32 + q31) * KROW + sc * 8]);
            s0v = __builtin_amdgcn_mfma_f32_32x32x16_bf16(k0, qf[dt], s0v, 0, 0, 0);
            s1v = __builtin_amdgcn_mfma_f32_32x32x16_bf16(k1, qf[dt], s1v, 0, 0, 0);
        }
        __builtin_amdgcn_s_setprio(0);

        // ---- softmax + packed cvt + permlane32_swap exchange -> pa[4] ----
        bf16x8 pa[4];
#pragma unroll
        for (int kv32 = 0; kv32 < 2; ++kv32) {
            i32x4 ukg[4];
#pragma unroll
            for (int g = 0; g < 4; ++g)
                ukg[g] = *reinterpret_cast<const i32x4*>(&ub[c][32 * kv32 + 8 * g + 4 * hi]);

            unsigned int dw[4][2];
#pragma unroll
            for (int g = 0; g < 4; ++g) {
                float v0 = __builtin_fmaf((kv32 ? s1v : s0v)[4 * g + 0], lscale,
                                          (uq == ukg[g][0]) ? cbias : cnob);
                float v1 = __builtin_fmaf((kv32 ? s1v : s0v)[4 * g + 1], lscale,
                                          (uq == ukg[g][1]) ? cbias : cnob);
                float v2 = __builtin_fmaf((kv32 ? s1v : s0v)[4 * g + 2], lscale,
                                          (uq == ukg[g][2]) ? cbias : cnob);
                float v3 = __builtin_fmaf((kv32 ? s1v : s0v)[4 * g + 3], lscale,
                                          (uq == ukg[g][3]) ? cbias : cnob);
                float p0 = __builtin_amdgcn_exp2f(v0);
                float p1 = __builtin_amdgcn_exp2f(v1);
                float p2 = __builtin_amdgcn_exp2f(v2);
                float p3 = __builtin_amdgcn_exp2f(v3);
                lsum += (p0 + p1) + (p2 + p3);
                dw[g][0] = cvtpk(p0, p1);    // low16=p0, high16=p1 (RNE)
                dw[g][1] = cvtpk(p2, p3);
            }

            // swap(dw[2kt], dw[2kt+1]): X'=h'=0 halves, Y'=h'=1 halves.
            // pa dwords = {X'_0, X'_1, Y'_0, Y'_1} (j=0..7 = 4h'+i).
#pragma unroll
            for (int kt = 0; kt < 2; ++kt) {
                v2i sw0 = __builtin_amdgcn_permlane32_swap(
                    (int)dw[2 * kt][0], (int)dw[2 * kt + 1][0], false, false);
                v2i sw1 = __builtin_amdgcn_permlane32_swap(
                    (int)dw[2 * kt][1], (int)dw[2 * kt + 1][1], false, false);
                union { unsigned int u[4]; bf16x8 v; } pu;
                pu.u[0] = (unsigned int)sw0[0];
                pu.u[1] = (unsigned int)sw1[0];
                pu.u[2] = (unsigned int)sw0[1];
                pu.u[3] = (unsigned int)sw1[1];
                pa[kv32 * 2 + kt] = pu.v;
            }
        }

        // ---- write prefetched K/u into idle buffer (kreg dies here) ----
#pragma unroll
        for (int p = 0; p < 4; ++p) {
            int slot = p * 256 + t;
            int row = slot >> 4, seg = slot & 15;
            int ss = seg ^ (row & 15);
            *reinterpret_cast<uint4*>(&kb[c ^ 1][row * KROW + ss * 8]) = kreg[p];
        }
        if (t < JT) ub[c ^ 1][t] = ureg;

        // ---- PV: O[q][d] += P @ V  (B[n=d][k=kv] from vb rows) ----
        __builtin_amdgcn_s_setprio(1);
#pragma unroll
        for (int nt = 0; nt < 4; ++nt) {
            int row = nt * 32 + q31;                 // d-row of vb
#pragma unroll
            for (int ktg = 0; ktg < 4; ++ktg) {
                int seg = ktg * 2 + hi;              // padded rows: no XOR
                bf16x8 b = *reinterpret_cast<const bf16x8*>(&vb[c][row * VROW + seg * 8]);
                o[nt] = __builtin_amdgcn_mfma_f32_32x32x16_bf16(pa[ktg], b, o[nt], 0, 0, 0);
            }
        }
        __builtin_amdgcn_s_setprio(0);

        // ---- write prefetched V into idle buffer ----
#pragma unroll
        for (int p = 0; p < 4; ++p) {
            int slot = p * 256 + t;
            int row = slot >> 3, seg = slot & 7;
            *reinterpret_cast<uint4*>(&vb[c ^ 1][row * VROW + seg * 8]) = vreg[p];
        }

        __syncthreads();   // single barrier per tile
        c ^= 1;
    }

    // ---- epilogue ----
    lsum += __shfl_xor(lsum, 32, 64);   // combine the two k-halves of q=q31

    if (out != nullptr) {
        bool lbad = !(lsum > 0.f) || !(lsum < 3.0e38f);
        float inv = 1.0f / lsum;
        if (hi == 0) lbuf[wave][q31] = lbad ? -1.0f : inv;
        __syncthreads();
        f32x4 ivg[4];
#pragma unroll
        for (int g = 0; g < 4; ++g)
            ivg[g] = *reinterpret_cast<const f32x4*>(&lbuf[wave][8 * g + 4 * hi]);
#pragma unroll
        for (int nt = 0; nt < 4; ++nt)
#pragma unroll
            for (int g = 0; g < 4; ++g)
#pragma unroll
                for (int i = 0; i < 4; ++i) {
                    int row = r0w + 8 * g + 4 * hi + i;
                    float iv = ivg[g][i];
                    float v = o[nt][4 * g + i] * iv;
                    if (v != v) v = 12345.0f;
                    if (iv < 0.f) v = 23456.0f;
                    out[(size_t)row * DIM + nt * 32 + q31] = v;
                }
    } else {
        const size_t base = (size_t)split * N_TOK;
        if (hi == 0) pl[base + r0w + q31] = lsum;
#pragma unroll
        for (int nt = 0; nt < 4; ++nt)
#pragma unroll
            for (int g = 0; g < 4; ++g)
#pragma unroll
                for (int i = 0; i < 4; ++i) {
                    int row = r0w + 8 * g + 4 * hi + i;
                    pO[(base + row) * DIM + nt * 32 + q31] = o[nt][4 * g + i];
                }
    }
}

// ---------------------------------------------------------------------------
// Merge: out[row] = (sum_s pO[s][row]) / (sum_s pl[s][row]).
// ---------------------------------------------------------------------------
__global__ __launch_bounds__(256)
void merge_kernel(const float* __restrict__ pO, const float* __restrict__ pl,
                  float* __restrict__ out, int ns)
{
    const int t = threadIdx.x;
    const int wave = t >> 6, lane = t & 63;
    const int row = blockIdx.x * 4 + wave;
    const int c = lane * 2;

    float l = 0.f;
    for (int s = 0; s < ns; ++s) l += pl[(size_t)s * N_TOK + row];
    bool lbad = !(l > 0.f) || !(l < 3.0e38f);
    float inv = 1.0f / l;

    float a0 = 0.f, a1 = 0.f;
    for (int s = 0; s < ns; ++s) {
        const float2 v = *reinterpret_cast<const float2*>(
            &pO[((size_t)s * N_TOK + row) * DIM + c]);
        a0 += v.x; a1 += v.y;
    }
    float v0 = a0 * inv, v1 = a1 * inv;
    if (v0 != v0) v0 = 12345.0f;
    if (v1 != v1) v1 = 12345.0f;
    if (lbad) { v0 = 23456.0f; v1 = 23456.0f; }
    float2 res; res.x = v0; res.y = v1;
    *reinterpret_cast<float2*>(&out[(size_t)row * DIM + c]) = res;
}

// ---------------------------------------------------------------------------
extern "C" void kernel_launch(void* const* d_in, const int* in_sizes, int n_in,
                              void* d_out, int out_size, void* d_ws, size_t ws_size,
                              hipStream_t stream)
{
    float* out = (float*)d_out;

    bool ok = (n_in == 5) &&
              in_sizes[0] == N_TOK * DIM && in_sizes[1] == N_TOK &&
              in_sizes[2] == DIM * DIM && in_sizes[3] == DIM * DIM &&
              in_sizes[4] == DIM * DIM && out_size == N_TOK * DIM;
    if (!ok) { marker_kernel<<<8192, 256, 0, stream>>>(out, 5555.f); return; }

    const float*        xf  = (const float*)d_in[0];
    const unsigned int* u32 = (const unsigned int*)d_in[1];
    const float*        wqf = (const float*)d_in[2];
    const float*        wkf = (const float*)d_in[3];
    const float*        wvf = (const float*)d_in[4];

    char* ws = (char*)d_ws;
    size_t off = 0;
    unsigned short* Q  = (unsigned short*)(ws + off); off += (size_t)N_TOK * DIM * 2;   // 4 MB
    unsigned short* K  = (unsigned short*)(ws + off); off += (size_t)N_TOK * DIM * 2;   // 4 MB
    unsigned short* Vt = (unsigned short*)(ws + off); off += (size_t)N_TOK * DIM * 2;   // 4 MB
    unsigned short* xb = (unsigned short*)(ws + off); off += (size_t)N_TOK * DIM * 2;   // 4 MB
    unsigned short* wb = (unsigned short*)(ws + off); off += (size_t)3 * DIM * DIM * 2; // 96 KB

    if (ws_size < off) { marker_kernel<<<8192, 256, 0, stream>>>(out, 4444.f); return; }

    // R8-proven config: nsplit=4, grid (128,4) = 512 blocks = 2 blocks/CU.
    const size_t per_split = (size_t)N_TOK * DIM * 4 + (size_t)N_TOK * 4;
    int nsplit = 1;
    if (ws_size >= off + 4 * per_split)      nsplit = 4;
    else if (ws_size >= off + 2 * per_split) nsplit = 2;

    prep_kernel<<<N_TOK * DIM / 4 / 256, 256, 0, stream>>>(xf, wqf, wkf, wvf, xb, wb);
    qkv_kernel<<<dim3(N_TOK / 64, 3), 256, 0, stream>>>(xb, wb, Q, K, Vt);

    if (nsplit >= 2) {
        float* pO = (float*)(ws + off);
        float* pl = (float*)(ws + off + (size_t)nsplit * N_TOK * DIM * 4);
        flash_kernel<<<dim3(N_TOK / 128, nsplit), 256, 0, stream>>>(
            Q, K, Vt, u32, N_TOK / nsplit, pO, pl, nullptr);
        merge_kernel<<<N_TOK / 4, 256, 0, stream>>>(pO, pl, out, nsplit);
    } else {
        flash_kernel<<<dim3(N_TOK / 128, 1), 256, 0, stream>>>(
            Q, K, Vt, u32, N_TOK, nullptr, nullptr, out);
    }
}